// Round 1
// baseline (141.523 us; speedup 1.0000x reference)
//
#include <hip/hip_runtime.h>
#include <hip/hip_bf16.h>

// Problem constants (fixed by the reference setup)
#define H_DIM  128
#define NGRAPH 8192
#define NTOTAL 409600
#define CHUNK  64          // nodes per K2 block

typedef __attribute__((ext_vector_type(8))) short s16x8;   // 8 bf16 (4 VGPRs)
typedef __attribute__((ext_vector_type(4))) float f32x4;   // MFMA accumulator

__device__ __forceinline__ unsigned short f2bf(float f) {
    unsigned int u = __float_as_uint(f);
    unsigned int r = u + 0x7fffu + ((u >> 16) & 1u);   // RNE
    return (unsigned short)(r >> 16);
}
__device__ __forceinline__ float bf2f(unsigned short h) {
    return __uint_as_float(((unsigned int)h) << 16);
}

// ---------------- K0: W2 f32 -> bf16 (row-major [h][k]) ----------------
__global__ void k0_w2(const float* __restrict__ W2w, unsigned short* __restrict__ w2bf) {
    int i = blockIdx.x * 256 + threadIdx.x;   // grid covers exactly 128*128
    w2bf[i] = f2bf(W2w[i]);
}

// ---------------- K1: v_n gather + a_g = v_n @ W1^T + (W1_b + W2_b) ----
__global__ __launch_bounds__(128) void k1_ag(
    const float* __restrict__ node_emb,
    const int*   __restrict__ last_idx,
    const float* __restrict__ W1w,
    const float* __restrict__ W1b,
    const float* __restrict__ W2b,
    float* __restrict__ a_g,
    float* __restrict__ v_n)
{
    __shared__ float vn[4][H_DIM];
    const int tid = threadIdx.x;
    const int g0  = blockIdx.x * 4;
    #pragma unroll
    for (int g = 0; g < 4; g++) {
        int li = last_idx[g0 + g];
        float v = node_emb[(size_t)li * H_DIM + tid];
        vn[g][tid] = v;
        v_n[(size_t)(g0 + g) * H_DIM + tid] = v;
    }
    __syncthreads();
    float b = W1b[tid] + W2b[tid];
    float a0 = b, a1 = b, a2 = b, a3 = b;
    const float* wrow = W1w + (size_t)tid * H_DIM;
    #pragma unroll 8
    for (int k = 0; k < H_DIM; k += 4) {
        float4 w = *reinterpret_cast<const float4*>(wrow + k);
        a0 += w.x * vn[0][k] + w.y * vn[0][k+1] + w.z * vn[0][k+2] + w.w * vn[0][k+3];
        a1 += w.x * vn[1][k] + w.y * vn[1][k+1] + w.z * vn[1][k+2] + w.w * vn[1][k+3];
        a2 += w.x * vn[2][k] + w.y * vn[2][k+1] + w.z * vn[2][k+2] + w.w * vn[2][k+3];
        a3 += w.x * vn[3][k] + w.y * vn[3][k+1] + w.z * vn[3][k+2] + w.w * vn[3][k+3];
    }
    a_g[(size_t)(g0 + 0) * H_DIM + tid] = a0;
    a_g[(size_t)(g0 + 1) * H_DIM + tid] = a1;
    a_g[(size_t)(g0 + 2) * H_DIM + tid] = a2;
    a_g[(size_t)(g0 + 3) * H_DIM + tid] = a3;
}

// ---------------- K2: fused z = node@W2^T + a_g[seg], alpha, s_g -------
// 6400 blocks x 256 threads (4 waves). Each block: 64 nodes.
// Waves tiled 2(m) x 2(n): each wave owns 32 rows x 64 cols of z.
__global__ __launch_bounds__(256) void k2_main(
    const float* __restrict__ node_emb,
    const float* __restrict__ num_count,
    const int*   __restrict__ seg_ids,
    const float* __restrict__ a_g,
    const unsigned short* __restrict__ w2bf,
    const float* __restrict__ q_w,
    const float* __restrict__ q_b,
    float* __restrict__ s_g)
{
    __shared__ __align__(16) char ndA[CHUNK * 256];    // 64 rows x 128 bf16, swizzled (16 KB)
    __shared__ __align__(16) char w2s[H_DIM * 256];    // 128 rows x 128 bf16, swizzled (32 KB)
    __shared__ float alphaLds[CHUNK];
    __shared__ float coefLds[CHUNK];
    __shared__ int   segLds[CHUNK];

    const int tid = threadIdx.x;
    const int nb  = blockIdx.x * CHUNK;

    // --- stage node chunk: f32 global (coalesced) -> bf16 LDS, XOR swizzled ---
    const float4* src4 = reinterpret_cast<const float4*>(node_emb + (size_t)nb * H_DIM);
    #pragma unroll
    for (int i = 0; i < 8; i++) {
        int f4 = i * 256 + tid;              // float4 index 0..2047
        float4 v = src4[f4];
        int fo  = f4 << 2;                   // f32 flat offset
        int row = fo >> 7;
        int col = fo & 127;
        int byte = (row << 8) | (col << 1);
        byte ^= (row & 7) << 4;
        ushort4 b;
        b.x = f2bf(v.x); b.y = f2bf(v.y); b.z = f2bf(v.z); b.w = f2bf(v.w);
        *reinterpret_cast<ushort4*>(ndA + byte) = b;
    }
    // --- stage W2 bf16 -> LDS, XOR swizzled ---
    const uint4* wsrc = reinterpret_cast<const uint4*>(w2bf);
    #pragma unroll
    for (int i = 0; i < 8; i++) {
        int c = i * 256 + tid;               // 16B chunk index 0..2047
        uint4 v = wsrc[c];
        int byte = c << 4;
        int row  = byte >> 8;
        *reinterpret_cast<uint4*>(w2s + (byte ^ ((row & 7) << 4))) = v;
    }
    if (tid < CHUNK) {
        segLds[tid]   = seg_ids[nb + tid];
        alphaLds[tid] = 0.f;
    }
    __syncthreads();

    const int lane = tid & 63;
    const int wid  = tid >> 6;
    const int wm = wid >> 1;     // 0..1 -> m offset wm*32
    const int wn = wid & 1;      // 0..1 -> n offset wn*64
    const int l16 = lane & 15, lq = lane >> 4;

    f32x4 acc[2][4];
    #pragma unroll
    for (int mt = 0; mt < 2; mt++)
        #pragma unroll
        for (int nt = 0; nt < 4; nt++)
            acc[mt][nt] = f32x4{0.f, 0.f, 0.f, 0.f};

    // --- MFMA: z[m][h] = sum_k node[m][k] * W2[h][k] ---
    #pragma unroll
    for (int ks = 0; ks < 4; ks++) {
        s16x8 af[2];
        #pragma unroll
        for (int mt = 0; mt < 2; mt++) {
            int row  = wm * 32 + mt * 16 + l16;
            int byte = (row << 8) | ((lq * 8 + ks * 32) << 1);
            byte ^= (row & 7) << 4;
            af[mt] = *reinterpret_cast<const s16x8*>(ndA + byte);
        }
        s16x8 bfr[4];
        #pragma unroll
        for (int nt = 0; nt < 4; nt++) {
            int row  = wn * 64 + nt * 16 + l16;
            int byte = (row << 8) | ((lq * 8 + ks * 32) << 1);
            byte ^= (row & 7) << 4;
            bfr[nt] = *reinterpret_cast<const s16x8*>(w2s + byte);
        }
        #pragma unroll
        for (int mt = 0; mt < 2; mt++)
            #pragma unroll
            for (int nt = 0; nt < 4; nt++)
                acc[mt][nt] = __builtin_amdgcn_mfma_f32_16x16x32_bf16(
                                  af[mt], bfr[nt], acc[mt][nt], 0, 0, 0);
    }

    // --- alpha: sum_h sigmoid(z + a_g[seg][h]) * q_w[h] ---
    float qv[4];
    #pragma unroll
    for (int nt = 0; nt < 4; nt++) qv[nt] = q_w[wn * 64 + nt * 16 + l16];

    #pragma unroll
    for (int mt = 0; mt < 2; mt++) {
        #pragma unroll
        for (int r = 0; r < 4; r++) {
            int m    = wm * 32 + mt * 16 + lq * 4 + r;   // D row = (lane>>4)*4 + r
            int sgid = segLds[m];
            const float* agr = a_g + (size_t)sgid * H_DIM;
            float p = 0.f;
            #pragma unroll
            for (int nt = 0; nt < 4; nt++) {
                int h = wn * 64 + nt * 16 + l16;         // D col = lane&15
                float z = acc[mt][nt][r] + agr[h];
                float g = 1.f / (1.f + __expf(-z));
                p += g * qv[nt];
            }
            p += __shfl_xor(p, 1, 64);
            p += __shfl_xor(p, 2, 64);
            p += __shfl_xor(p, 4, 64);
            p += __shfl_xor(p, 8, 64);
            if (l16 == 0) atomicAdd(&alphaLds[m], p);
        }
    }
    __syncthreads();
    if (tid < CHUNK) {
        coefLds[tid] = num_count[nb + tid] * (alphaLds[tid] + q_b[0]);
    }
    __syncthreads();

    // --- segment-sum: s_g[seg][h] += sum_m coef[m] * node[m][h] ---
    {
        int h  = tid & 127;
        int mh = tid >> 7;       // 0/1: which 32-node half
        int m0 = mh * 32;
        float acs = 0.f;
        int cur = segLds[m0];
        #pragma unroll 4
        for (int m = m0; m < m0 + 32; m++) {
            int s = segLds[m];
            if (s != cur) {
                atomicAdd(s_g + (size_t)cur * H_DIM + h, acs);
                acs = 0.f; cur = s;
            }
            int byte = (m << 8) | (h << 1);
            byte ^= (m & 7) << 4;
            unsigned short nv = *reinterpret_cast<const unsigned short*>(ndA + byte);
            acs += coefLds[m] * bf2f(nv);
        }
        atomicAdd(s_g + (size_t)cur * H_DIM + h, acs);
    }
}

// ---------------- K3: s_h = [v_n | s_g] @ W3^T + W3_b ------------------
__global__ __launch_bounds__(128) void k3_out(
    const float* __restrict__ v_n,
    const float* __restrict__ s_g,
    const float* __restrict__ W3w,
    const float* __restrict__ W3b,
    float* __restrict__ out)
{
    __shared__ float cat[8][2 * H_DIM];
    const int tid = threadIdx.x;
    const int g0  = blockIdx.x * 8;
    #pragma unroll
    for (int g = 0; g < 8; g++) {
        cat[g][tid]         = v_n[(size_t)(g0 + g) * H_DIM + tid];
        cat[g][H_DIM + tid] = s_g[(size_t)(g0 + g) * H_DIM + tid];
    }
    __syncthreads();
    float acc[8];
    float b = W3b[tid];
    #pragma unroll
    for (int g = 0; g < 8; g++) acc[g] = b;
    const float* wrow = W3w + (size_t)tid * (2 * H_DIM);
    for (int k = 0; k < 2 * H_DIM; k += 4) {
        float4 w = *reinterpret_cast<const float4*>(wrow + k);
        #pragma unroll
        for (int g = 0; g < 8; g++)
            acc[g] += w.x * cat[g][k] + w.y * cat[g][k+1]
                    + w.z * cat[g][k+2] + w.w * cat[g][k+3];
    }
    #pragma unroll
    for (int g = 0; g < 8; g++)
        out[(size_t)(g0 + g) * H_DIM + tid] = acc[g];
}

extern "C" void kernel_launch(void* const* d_in, const int* in_sizes, int n_in,
                              void* d_out, int out_size, void* d_ws, size_t ws_size,
                              hipStream_t stream) {
    const float* node_emb  = (const float*)d_in[0];
    const float* num_count = (const float*)d_in[1];
    // d_in[2] sections: unused (segment_ids + last_idx suffice)
    const int*   seg_ids   = (const int*)d_in[3];
    const int*   last_idx  = (const int*)d_in[4];
    // d_in[5..8] item_embedding_table / user_embedding / u_n_repeat / max_item_id: unused
    const float* W1w = (const float*)d_in[9];
    const float* W1b = (const float*)d_in[10];
    const float* W2w = (const float*)d_in[11];
    const float* W2b = (const float*)d_in[12];
    const float* qw  = (const float*)d_in[13];
    const float* qb  = (const float*)d_in[14];
    const float* W3w = (const float*)d_in[15];
    const float* W3b = (const float*)d_in[16];
    float* out = (float*)d_out;

    char* ws = (char*)d_ws;
    float* a_g = (float*)(ws);                          // 8192*128*4 = 4 MB
    float* v_n = (float*)(ws + (4u  << 20));            // 4 MB
    float* s_g = (float*)(ws + (8u  << 20));            // 4 MB
    unsigned short* w2bf = (unsigned short*)(ws + (12u << 20));  // 32 KB

    hipMemsetAsync(s_g, 0, (size_t)NGRAPH * H_DIM * sizeof(float), stream);
    k0_w2 <<<64,   256, 0, stream>>>(W2w, w2bf);
    k1_ag <<<NGRAPH / 4, 128, 0, stream>>>(node_emb, last_idx, W1w, W1b, W2b, a_g, v_n);
    k2_main<<<NTOTAL / CHUNK, 256, 0, stream>>>(node_emb, num_count, seg_ids, a_g,
                                                w2bf, qw, qb, s_g);
    k3_out<<<NGRAPH / 8, 128, 0, stream>>>(v_n, s_g, W3w, W3b, out);
}